// Round 1
// baseline (279.008 us; speedup 1.0000x reference)
//
#include <hip/hip_runtime.h>

#define N_NODES   100000
#define N_CLASSES 16
#define N_EDGES   3200000
#define KE        8                     // edges per thread, edge pass

// ===================== fp8 e4m3 helpers =====================
// Manual encode produces OCP e4m3fn bit patterns (bias 7, max 448),
// so the HW decoder v_cvt_pk_f32_fp8 reads them exactly. (verified pass)

__device__ __forceinline__ unsigned f2fp8(float f) {
    unsigned u = __float_as_uint(f);
    unsigned s = (u >> 24) & 0x80u;
    float g = fabsf(f) * 0x1p-120f;
    unsigned gu = __float_as_uint(g);
    gu += 0x7FFFFu + ((gu >> 20) & 1u);       // RNE at bit 20
    unsigned mag = gu >> 20;
    if (mag > 0x7Eu) mag = 0x7Eu;             // clamp to 448
    return s | mag;
}

__device__ __forceinline__ float fp82f(unsigned b) {
    unsigned u = ((b & 0x80u) << 24) | ((b & 0x7Fu) << 20);
    return __uint_as_float(u) * 0x1p120f;
}

#if defined(__has_builtin)
#if __has_builtin(__builtin_amdgcn_cvt_pk_f32_fp8)
#define HAVE_HW_FP8 1
#endif
#endif

#ifdef HAVE_HW_FP8
typedef float v2f __attribute__((ext_vector_type(2)));
__device__ __forceinline__ float ssd4(unsigned a, unsigned b) {
    v2f a0 = __builtin_amdgcn_cvt_pk_f32_fp8((int)a, false);
    v2f a1 = __builtin_amdgcn_cvt_pk_f32_fp8((int)a, true);
    v2f b0 = __builtin_amdgcn_cvt_pk_f32_fp8((int)b, false);
    v2f b1 = __builtin_amdgcn_cvt_pk_f32_fp8((int)b, true);
    float d0 = a0.x - b0.x;
    float d1 = a0.y - b0.y;
    float d2 = a1.x - b1.x;
    float d3 = a1.y - b1.y;
    return d0 * d0 + d1 * d1 + d2 * d2 + d3 * d3;
}
#else
__device__ __forceinline__ float ssd4(unsigned a, unsigned b) {
    float s = 0.0f;
#pragma unroll
    for (int i = 0; i < 4; ++i) {
        float va = fp82f((a >> (8 * i)) & 0xFFu);
        float vb = fp82f((b >> (8 * i)) & 0xFFu);
        float d = va - vb;
        s += d * d;
    }
    return s;
}
#endif

// ===================== zero degree + out =====================
// Kernel (not hipMemsetAsync) to stay squarely inside graph-capture-safe ops.

__global__ __launch_bounds__(256) void lap_zero(float* __restrict__ degree,
                                                float* __restrict__ out) {
    const int i = blockIdx.x * blockDim.x + threadIdx.x;
    if (i == 0) out[0] = 0.0f;
    const int n = i * 4;
    if (n < N_NODES)                      // N_NODES % 4 == 0, exact coverage
        *(float4*)(degree + n) = make_float4(0.f, 0.f, 0.f, 0.f);
}

// ===================== degree: direct global fp32 atomics =====================
// 3.2M fire-and-forget global_atomic_add_f32 into a 400 KB L2-resident array.
// Replaces the R=5 LDS-histogram machinery (5x edge re-read + 20.4 MB shadow
// write + 102-deep latency-bound reduce).

__global__ __launch_bounds__(256) void lap_degree_atomic(
        const int* __restrict__ rows, const float* __restrict__ w,
        float* __restrict__ degree) {
    const int g = blockIdx.x * blockDim.x + threadIdx.x;
    const int e = g * 4;                  // grid sized exactly: E/4 threads
    if (e >= N_EDGES) return;
    const int4   r4 = *(const int4*)(rows + e);
    const float4 w4 = *(const float4*)(w + e);
    atomicAdd(&degree[r4.x], w4.x);       // no return use -> no-ret atomic
    atomicAdd(&degree[r4.y], w4.y);
    atomicAdd(&degree[r4.z], w4.z);
    atomicAdd(&degree[r4.w], w4.w);
}

// ===================== rsqrt(degree) -> fp8 yhat =====================

__global__ __launch_bounds__(256) void lap_yhat_deg(
        const float* __restrict__ degree,
        const float* __restrict__ y,
        unsigned char* __restrict__ yhat) {
    const int n = blockIdx.x * blockDim.x + threadIdx.x;
    if (n >= N_NODES) return;
    const float inv = rsqrtf(degree[n]);

    const float4* yr = (const float4*)(y + (size_t)n * N_CLASSES);
    uint4 o;
    unsigned* op = (unsigned*)&o;
#pragma unroll
    for (int j = 0; j < 4; ++j) {
        float4 v = yr[j];
        op[j] =  f2fp8(v.x * inv)
              | (f2fp8(v.y * inv) << 8)
              | (f2fp8(v.z * inv) << 16)
              | (f2fp8(v.w * inv) << 24);
    }
    *(uint4*)(yhat + (size_t)n * N_CLASSES) = o;
}

// ===================== edge pass: fp8 HW decode, fused mean (unchanged) =====================

__global__ void lap_edge_fp8(const int* __restrict__ rows,
                             const int* __restrict__ cols,
                             const float* __restrict__ w,
                             const unsigned char* __restrict__ yhat,
                             float* __restrict__ out) {
    const int tid = blockIdx.x * blockDim.x + threadIdx.x;
    const long e0 = (long)tid * KE;
    float local = 0.0f;
    if (e0 < N_EDGES) {
        int4   ra = *(const int4*)(rows + e0);
        int4   rb = *(const int4*)(rows + e0 + 4);
        int4   ca = *(const int4*)(cols + e0);
        int4   cb = *(const int4*)(cols + e0 + 4);
        float4 wa = *(const float4*)(w + e0);
        float4 wb = *(const float4*)(w + e0 + 4);

        const int ri[KE] = {ra.x, ra.y, ra.z, ra.w, rb.x, rb.y, rb.z, rb.w};
        const int ci[KE] = {ca.x, ca.y, ca.z, ca.w, cb.x, cb.y, cb.z, cb.w};
        const float wv[KE] = {wa.x, wa.y, wa.z, wa.w, wb.x, wb.y, wb.z, wb.w};

        uint4 A[KE], B[KE];
#pragma unroll
        for (int k = 0; k < KE; ++k) {
            A[k] = *(const uint4*)(yhat + (size_t)ri[k] * N_CLASSES);
            B[k] = *(const uint4*)(yhat + (size_t)ci[k] * N_CLASSES);
        }
#pragma unroll
        for (int k = 0; k < KE; ++k) {
            float s = ssd4(A[k].x, B[k].x) + ssd4(A[k].y, B[k].y)
                    + ssd4(A[k].z, B[k].z) + ssd4(A[k].w, B[k].w);
            local += wv[k] * sqrtf(s);
        }
    }
#pragma unroll
    for (int off = 32; off > 0; off >>= 1) local += __shfl_down(local, off, 64);
    __shared__ float sm[4];
    const int lane = threadIdx.x & 63;
    const int wid  = threadIdx.x >> 6;
    if (lane == 0) sm[wid] = local;
    __syncthreads();
    if (threadIdx.x == 0)
        atomicAdd(out, (sm[0] + sm[1] + sm[2] + sm[3]) * (1.0f / (float)N_EDGES));
}

// ===================== low fallback (tiny ws) =====================

__global__ void lap_degree_kernel(const int* __restrict__ rows,
                                  const float* __restrict__ w,
                                  float* __restrict__ degree) {
    int i = blockIdx.x * blockDim.x + threadIdx.x;
    if (i < N_EDGES) atomicAdd(&degree[rows[i]], w[i]);
}

__global__ void lap_invd_kernel(const float* __restrict__ degree,
                                float* __restrict__ invd) {
    int i = blockIdx.x * blockDim.x + threadIdx.x;
    if (i < N_NODES) invd[i] = rsqrtf(degree[i]);
}

__global__ void lap_edge_kernel(const int* __restrict__ rows,
                                const int* __restrict__ cols,
                                const float* __restrict__ w,
                                const float* __restrict__ y,
                                const float* __restrict__ invd,
                                float* __restrict__ out) {
    int i = blockIdx.x * blockDim.x + threadIdx.x;
    float local = 0.0f;
    if (i < N_EDGES) {
        int r = rows[i], c = cols[i];
        float dr = invd[r], dc = invd[c];
        const float4* yr = (const float4*)(y + (size_t)r * N_CLASSES);
        const float4* yc = (const float4*)(y + (size_t)c * N_CLASSES);
        float s = 0.0f;
#pragma unroll
        for (int j = 0; j < N_CLASSES / 4; ++j) {
            float4 a = yr[j], b = yc[j];
            float d0 = a.x * dr - b.x * dc;
            float d1 = a.y * dr - b.y * dc;
            float d2 = a.z * dr - b.z * dc;
            float d3 = a.w * dr - b.w * dc;
            s += d0 * d0 + d1 * d1 + d2 * d2 + d3 * d3;
        }
        local = w[i] * sqrtf(s);
    }
#pragma unroll
    for (int off = 32; off > 0; off >>= 1) local += __shfl_down(local, off, 64);
    __shared__ float sm[4];
    int lane = threadIdx.x & 63, wid = threadIdx.x >> 6;
    if (lane == 0) sm[wid] = local;
    __syncthreads();
    if (threadIdx.x == 0)
        atomicAdd(out, (sm[0] + sm[1] + sm[2] + sm[3]) * (1.0f / (float)N_EDGES));
}

// ===================== launch =====================

extern "C" void kernel_launch(void* const* d_in, const int* in_sizes, int n_in,
                              void* d_out, int out_size, void* d_ws, size_t ws_size,
                              hipStream_t stream) {
    const int*   edge_index = (const int*)d_in[0];   // [rows | cols]
    const float* w          = (const float*)d_in[1];
    const float* y          = (const float*)d_in[2];
    float*       out        = (float*)d_out;

    const int* rows = edge_index;
    const int* cols = edge_index + N_EDGES;
    const int  B = 256;

    // layout: [degree: N f32 (400 KB)][yhat: N*16 fp8 bytes (1.6 MB)]
    const size_t deg_bytes = (size_t)N_NODES * sizeof(float);
    const size_t need      = deg_bytes + (size_t)N_NODES * N_CLASSES;

    const int edge_blocks = (N_EDGES / KE + B - 1) / B;   // 1563

    if (ws_size >= need) {
        float*         degree = (float*)d_ws;
        unsigned char* yhat   = (unsigned char*)d_ws + deg_bytes;   // 400000 % 16 == 0

        lap_zero<<<(N_NODES / 4 + B - 1) / B, B, 0, stream>>>(degree, out);   // 98 blocks
        lap_degree_atomic<<<N_EDGES / 4 / B, B, 0, stream>>>(rows, w, degree); // 3125 blocks
        lap_yhat_deg<<<(N_NODES + B - 1) / B, B, 0, stream>>>(degree, y, yhat);
        lap_edge_fp8<<<edge_blocks, B, 0, stream>>>(rows, cols, w, yhat, out);
    } else {
        float* degree = (float*)d_ws;
        float* invd   = degree + N_NODES;
        hipMemsetAsync(d_out, 0, sizeof(float), stream);
        hipMemsetAsync(d_ws, 0, (size_t)N_NODES * sizeof(float), stream);
        lap_degree_kernel<<<(N_EDGES + B - 1) / B, B, 0, stream>>>(rows, w, degree);
        lap_invd_kernel<<<(N_NODES + B - 1) / B, B, 0, stream>>>(degree, invd);
        lap_edge_kernel<<<(N_EDGES + B - 1) / B, B, 0, stream>>>(rows, cols, w, y, invd, out);
    }
}

// Round 2
// 140.920 us; speedup vs baseline: 1.9799x; 1.9799x over previous
//
#include <hip/hip_runtime.h>
#include <hip/hip_fp16.h>

#define N_NODES   100000
#define N_CLASSES 16
#define N_EDGES   3200000

// ---- degree: R=5 ranges, 80 KB dynamic LDS, 2 blocks/CU ----
#define R5        5
#define NPR5      20000                 // nodes per range
#define DYN5      (NPR5 * 4)            // 80000 B dynamic LDS
#define S5        102                   // slices -> 510 blocks
#define EPS5      31376                 // edges per slice (mult of 4; 102*31376 >= E)

// ---- degree fallback: static 50 KB, R=8 ----
#define R_ST      8
#define NPR_ST    12500
#define S_ST      64
#define EPS_ST    50000

#define B_DEG     1024
#define KE        8                     // edges per thread, edge pass

// ===================== fp8 e4m3 helpers =====================
// Manual encode produces OCP e4m3fn bit patterns (bias 7, max 448),
// so the HW decoder v_cvt_pk_f32_fp8 reads them exactly. (verified pass)

__device__ __forceinline__ unsigned f2fp8(float f) {
    unsigned u = __float_as_uint(f);
    unsigned s = (u >> 24) & 0x80u;
    float g = fabsf(f) * 0x1p-120f;
    unsigned gu = __float_as_uint(g);
    gu += 0x7FFFFu + ((gu >> 20) & 1u);       // RNE at bit 20
    unsigned mag = gu >> 20;
    if (mag > 0x7Eu) mag = 0x7Eu;             // clamp to 448
    return s | mag;
}

__device__ __forceinline__ float fp82f(unsigned b) {
    unsigned u = ((b & 0x80u) << 24) | ((b & 0x7Fu) << 20);
    return __uint_as_float(u) * 0x1p120f;
}

#if defined(__has_builtin)
#if __has_builtin(__builtin_amdgcn_cvt_pk_f32_fp8)
#define HAVE_HW_FP8 1
#endif
#endif

#ifdef HAVE_HW_FP8
typedef float v2f __attribute__((ext_vector_type(2)));
__device__ __forceinline__ float ssd4(unsigned a, unsigned b) {
    v2f a0 = __builtin_amdgcn_cvt_pk_f32_fp8((int)a, false);
    v2f a1 = __builtin_amdgcn_cvt_pk_f32_fp8((int)a, true);
    v2f b0 = __builtin_amdgcn_cvt_pk_f32_fp8((int)b, false);
    v2f b1 = __builtin_amdgcn_cvt_pk_f32_fp8((int)b, true);
    float d0 = a0.x - b0.x;
    float d1 = a0.y - b0.y;
    float d2 = a1.x - b1.x;
    float d3 = a1.y - b1.y;
    return d0 * d0 + d1 * d1 + d2 * d2 + d3 * d3;
}
#else
__device__ __forceinline__ float ssd4(unsigned a, unsigned b) {
    float s = 0.0f;
#pragma unroll
    for (int i = 0; i < 4; ++i) {
        float va = fp82f((a >> (8 * i)) & 0xFFu);
        float vb = fp82f((b >> (8 * i)) & 0xFFu);
        float d = va - vb;
        s += d * d;
    }
    return s;
}
#endif

// ===================== degree: R=5, dynamic 80 KB LDS =====================
// (byte-identical to the 160.5 us round-0 version — A/B control)

__global__ __launch_bounds__(B_DEG, 8) void lap_degree_r5(
        const int* __restrict__ rows, const float* __restrict__ w,
        __half* __restrict__ shadows, float* __restrict__ out) {
    extern __shared__ float hist[];
    const int b  = blockIdx.x;
    const int r  = b % R5;
    const int s  = b / R5;
    const int lo = r * NPR5;

    if (b == 0 && threadIdx.x == 0) out[0] = 0.0f;

    for (int i = threadIdx.x; i < NPR5; i += B_DEG) hist[i] = 0.0f;
    __syncthreads();

    const int base = s * EPS5;
    for (int g = threadIdx.x; g < EPS5 / 4; g += B_DEG) {
        const int e = base + g * 4;
        if (e >= N_EDGES) continue;          // tail slice guard (E % 4 == 0)
        int4   r4 = *(const int4*)(rows + e);
        float4 w4 = *(const float4*)(w + e);
        int t;
        t = r4.x - lo; if ((unsigned)t < (unsigned)NPR5) atomicAdd(&hist[t], w4.x);
        t = r4.y - lo; if ((unsigned)t < (unsigned)NPR5) atomicAdd(&hist[t], w4.y);
        t = r4.z - lo; if ((unsigned)t < (unsigned)NPR5) atomicAdd(&hist[t], w4.z);
        t = r4.w - lo; if ((unsigned)t < (unsigned)NPR5) atomicAdd(&hist[t], w4.w);
    }
    __syncthreads();

    __half* dst = shadows + (size_t)s * N_NODES + lo;
    for (int i = threadIdx.x; i < NPR5; i += B_DEG) dst[i] = __float2half(hist[i]);
}

// ===================== degree fallback: static 50 KB, R=8 =====================

__global__ __launch_bounds__(B_DEG) void lap_degree_static(
        const int* __restrict__ rows, const float* __restrict__ w,
        __half* __restrict__ shadows, float* __restrict__ out) {
    __shared__ float hist[NPR_ST];
    const int r  = blockIdx.x & (R_ST - 1);
    const int s  = blockIdx.x >> 3;
    const int lo = r * NPR_ST;

    if (blockIdx.x == 0 && threadIdx.x == 0) out[0] = 0.0f;

    for (int i = threadIdx.x; i < NPR_ST; i += B_DEG) hist[i] = 0.0f;
    __syncthreads();

    const int base = s * EPS_ST;
    for (int g = threadIdx.x; g < EPS_ST / 4; g += B_DEG) {
        const int e = base + g * 4;
        int4   r4 = *(const int4*)(rows + e);
        float4 w4 = *(const float4*)(w + e);
        int t;
        t = r4.x - lo; if ((unsigned)t < (unsigned)NPR_ST) atomicAdd(&hist[t], w4.x);
        t = r4.y - lo; if ((unsigned)t < (unsigned)NPR_ST) atomicAdd(&hist[t], w4.y);
        t = r4.z - lo; if ((unsigned)t < (unsigned)NPR_ST) atomicAdd(&hist[t], w4.z);
        t = r4.w - lo; if ((unsigned)t < (unsigned)NPR_ST) atomicAdd(&hist[t], w4.w);
    }
    __syncthreads();

    __half* dst = shadows + (size_t)s * N_NODES + lo;
    for (int i = threadIdx.x; i < NPR_ST; i += B_DEG) dst[i] = __float2half(hist[i]);
}

// ===================== parallel shadow reduce -> rsqrt -> fp8 yhat =====================
// Replaces the serial 102-deep per-thread reduce (latency-bound) with a
// 4-wave-parallel reduce: 64 nodes/block, wave wv sums slices {wv, wv+4, ...}
// into independent accumulators, LDS combine, wave 0 encodes fp8.

__global__ __launch_bounds__(256) void lap_yhat_par(
        const __half* __restrict__ shadows,
        const float* __restrict__ y,
        unsigned char* __restrict__ yhat, int S) {
    const int lane = threadIdx.x & 63;
    const int wv   = threadIdx.x >> 6;
    const int n    = blockIdx.x * 64 + lane;

    float a0 = 0.0f, a1 = 0.0f, a2 = 0.0f, a3 = 0.0f;
    if (n < N_NODES) {
        const __half* p = shadows + n;
        int s = wv;
        for (; s + 12 < S; s += 16) {            // 4 independent load streams
            a0 += __half2float(p[(size_t)(s)      * N_NODES]);
            a1 += __half2float(p[(size_t)(s + 4)  * N_NODES]);
            a2 += __half2float(p[(size_t)(s + 8)  * N_NODES]);
            a3 += __half2float(p[(size_t)(s + 12) * N_NODES]);
        }
        for (; s < S; s += 4)
            a0 += __half2float(p[(size_t)s * N_NODES]);
    }

    __shared__ float sm[4][64];
    sm[wv][lane] = (a0 + a1) + (a2 + a3);
    __syncthreads();

    if (wv == 0 && n < N_NODES) {
        const float deg = (sm[0][lane] + sm[1][lane]) + (sm[2][lane] + sm[3][lane]);
        const float inv = rsqrtf(deg);
        const float4* yr = (const float4*)(y + (size_t)n * N_CLASSES);
        uint4 o;
        unsigned* op = (unsigned*)&o;
#pragma unroll
        for (int j = 0; j < 4; ++j) {
            float4 v = yr[j];
            op[j] =  f2fp8(v.x * inv)
                  | (f2fp8(v.y * inv) << 8)
                  | (f2fp8(v.z * inv) << 16)
                  | (f2fp8(v.w * inv) << 24);
        }
        *(uint4*)(yhat + (size_t)n * N_CLASSES) = o;
    }
}

// ===================== edge pass: fp8 HW decode, fused mean =====================
// (byte-identical to round-0 — A/B control)

__global__ void lap_edge_fp8(const int* __restrict__ rows,
                             const int* __restrict__ cols,
                             const float* __restrict__ w,
                             const unsigned char* __restrict__ yhat,
                             float* __restrict__ out) {
    const int tid = blockIdx.x * blockDim.x + threadIdx.x;
    const long e0 = (long)tid * KE;
    float local = 0.0f;
    if (e0 < N_EDGES) {
        int4   ra = *(const int4*)(rows + e0);
        int4   rb = *(const int4*)(rows + e0 + 4);
        int4   ca = *(const int4*)(cols + e0);
        int4   cb = *(const int4*)(cols + e0 + 4);
        float4 wa = *(const float4*)(w + e0);
        float4 wb = *(const float4*)(w + e0 + 4);

        const int ri[KE] = {ra.x, ra.y, ra.z, ra.w, rb.x, rb.y, rb.z, rb.w};
        const int ci[KE] = {ca.x, ca.y, ca.z, ca.w, cb.x, cb.y, cb.z, cb.w};
        const float wv[KE] = {wa.x, wa.y, wa.z, wa.w, wb.x, wb.y, wb.z, wb.w};

        uint4 A[KE], B[KE];
#pragma unroll
        for (int k = 0; k < KE; ++k) {
            A[k] = *(const uint4*)(yhat + (size_t)ri[k] * N_CLASSES);
            B[k] = *(const uint4*)(yhat + (size_t)ci[k] * N_CLASSES);
        }
#pragma unroll
        for (int k = 0; k < KE; ++k) {
            float s = ssd4(A[k].x, B[k].x) + ssd4(A[k].y, B[k].y)
                    + ssd4(A[k].z, B[k].z) + ssd4(A[k].w, B[k].w);
            local += wv[k] * sqrtf(s);
        }
    }
#pragma unroll
    for (int off = 32; off > 0; off >>= 1) local += __shfl_down(local, off, 64);
    __shared__ float sm[4];
    const int lane = threadIdx.x & 63;
    const int wid  = threadIdx.x >> 6;
    if (lane == 0) sm[wid] = local;
    __syncthreads();
    if (threadIdx.x == 0)
        atomicAdd(out, (sm[0] + sm[1] + sm[2] + sm[3]) * (1.0f / (float)N_EDGES));
}

// ===================== low fallback (tiny ws) =====================

__global__ void lap_degree_kernel(const int* __restrict__ rows,
                                  const float* __restrict__ w,
                                  float* __restrict__ degree) {
    int i = blockIdx.x * blockDim.x + threadIdx.x;
    if (i < N_EDGES) atomicAdd(&degree[rows[i]], w[i]);
}

__global__ void lap_invd_kernel(const float* __restrict__ degree,
                                float* __restrict__ invd) {
    int i = blockIdx.x * blockDim.x + threadIdx.x;
    if (i < N_NODES) invd[i] = rsqrtf(degree[i]);
}

__global__ void lap_edge_kernel(const int* __restrict__ rows,
                                const int* __restrict__ cols,
                                const float* __restrict__ w,
                                const float* __restrict__ y,
                                const float* __restrict__ invd,
                                float* __restrict__ out) {
    int i = blockIdx.x * blockDim.x + threadIdx.x;
    float local = 0.0f;
    if (i < N_EDGES) {
        int r = rows[i], c = cols[i];
        float dr = invd[r], dc = invd[c];
        const float4* yr = (const float4*)(y + (size_t)r * N_CLASSES);
        const float4* yc = (const float4*)(y + (size_t)c * N_CLASSES);
        float s = 0.0f;
#pragma unroll
        for (int j = 0; j < N_CLASSES / 4; ++j) {
            float4 a = yr[j], b = yc[j];
            float d0 = a.x * dr - b.x * dc;
            float d1 = a.y * dr - b.y * dc;
            float d2 = a.z * dr - b.z * dc;
            float d3 = a.w * dr - b.w * dc;
            s += d0 * d0 + d1 * d1 + d2 * d2 + d3 * d3;
        }
        local = w[i] * sqrtf(s);
    }
#pragma unroll
    for (int off = 32; off > 0; off >>= 1) local += __shfl_down(local, off, 64);
    __shared__ float sm[4];
    int lane = threadIdx.x & 63, wid = threadIdx.x >> 6;
    if (lane == 0) sm[wid] = local;
    __syncthreads();
    if (threadIdx.x == 0)
        atomicAdd(out, (sm[0] + sm[1] + sm[2] + sm[3]) * (1.0f / (float)N_EDGES));
}

// ===================== launch =====================

extern "C" void kernel_launch(void* const* d_in, const int* in_sizes, int n_in,
                              void* d_out, int out_size, void* d_ws, size_t ws_size,
                              hipStream_t stream) {
    const int*   edge_index = (const int*)d_in[0];   // [rows | cols]
    const float* w          = (const float*)d_in[1];
    const float* y          = (const float*)d_in[2];
    float*       out        = (float*)d_out;

    const int* rows = edge_index;
    const int* cols = edge_index + N_EDGES;
    const int  B = 256;

    // layout: [shadows: S5*N halves (20.4 MB)][yhat: N*16 fp8 bytes]
    const size_t sh_bytes   = (size_t)S5 * N_NODES * sizeof(__half);
    const size_t need_super = sh_bytes + (size_t)N_NODES * N_CLASSES;

    const int edge_blocks = (N_EDGES / KE + B - 1) / B;   // 1563
    const int yhat_blocks = (N_NODES + 63) / 64;          // 1563

    if (ws_size >= need_super) {
        __half*        shadows = (__half*)d_ws;
        unsigned char* yhat    = (unsigned char*)d_ws + sh_bytes;

        hipError_t ok = hipFuncSetAttribute(
            reinterpret_cast<const void*>(lap_degree_r5),
            hipFuncAttributeMaxDynamicSharedMemorySize, DYN5);

        if (ok == hipSuccess) {
            lap_degree_r5<<<R5 * S5, B_DEG, DYN5, stream>>>(rows, w, shadows, out);
            lap_yhat_par<<<yhat_blocks, B, 0, stream>>>(shadows, y, yhat, S5);
        } else {
            lap_degree_static<<<R_ST * S_ST, B_DEG, 0, stream>>>(rows, w, shadows, out);
            lap_yhat_par<<<yhat_blocks, B, 0, stream>>>(shadows, y, yhat, S_ST);
        }
        lap_edge_fp8<<<edge_blocks, B, 0, stream>>>(rows, cols, w, yhat, out);
    } else {
        float* degree = (float*)d_ws;
        float* invd   = degree + N_NODES;
        hipMemsetAsync(d_out, 0, sizeof(float), stream);
        hipMemsetAsync(d_ws, 0, (size_t)N_NODES * sizeof(float), stream);
        lap_degree_kernel<<<(N_EDGES + B - 1) / B, B, 0, stream>>>(rows, w, degree);
        lap_invd_kernel<<<(N_NODES + B - 1) / B, B, 0, stream>>>(degree, invd);
        lap_edge_kernel<<<(N_EDGES + B - 1) / B, B, 0, stream>>>(rows, cols, w, y, invd, out);
    }
}

// Round 3
// 139.602 us; speedup vs baseline: 1.9986x; 1.0094x over previous
//
#include <hip/hip_runtime.h>
#include <hip/hip_fp16.h>

#define N_NODES   100000
#define N_CLASSES 16
#define N_EDGES   3200000

// ---- degree: R=2 ranges, fp16-packed hist, 100 KB dynamic LDS, 1 block/CU ----
#define R2        2
#define NPR2      50000                 // nodes per range (fp16 -> 100000 B LDS)
#define DYN2      (NPR2 * 2)            // 100000 B dynamic LDS
#define S2        128                   // slices -> grid 256 (1 block/CU, exact)
#define EPS2      25000                 // 128*25000 == N_EDGES exactly, no tail

// ---- degree fallback: static 50 KB fp32, R=8 ----
#define R_ST      8
#define NPR_ST    12500
#define S_ST      64
#define EPS_ST    50000

#define B_DEG     1024
#define KE        8                     // edges per thread, edge pass

// ===================== fp8 e4m3 helpers =====================
// Manual encode produces OCP e4m3fn bit patterns (bias 7, max 448),
// so the HW decoder v_cvt_pk_f32_fp8 reads them exactly. (verified pass)

__device__ __forceinline__ unsigned f2fp8(float f) {
    unsigned u = __float_as_uint(f);
    unsigned s = (u >> 24) & 0x80u;
    float g = fabsf(f) * 0x1p-120f;
    unsigned gu = __float_as_uint(g);
    gu += 0x7FFFFu + ((gu >> 20) & 1u);       // RNE at bit 20
    unsigned mag = gu >> 20;
    if (mag > 0x7Eu) mag = 0x7Eu;             // clamp to 448
    return s | mag;
}

__device__ __forceinline__ float fp82f(unsigned b) {
    unsigned u = ((b & 0x80u) << 24) | ((b & 0x7Fu) << 20);
    return __uint_as_float(u) * 0x1p120f;
}

#if defined(__has_builtin)
#if __has_builtin(__builtin_amdgcn_cvt_pk_f32_fp8)
#define HAVE_HW_FP8 1
#endif
#endif

#ifdef HAVE_HW_FP8
typedef float v2f __attribute__((ext_vector_type(2)));
__device__ __forceinline__ float ssd4(unsigned a, unsigned b) {
    v2f a0 = __builtin_amdgcn_cvt_pk_f32_fp8((int)a, false);
    v2f a1 = __builtin_amdgcn_cvt_pk_f32_fp8((int)a, true);
    v2f b0 = __builtin_amdgcn_cvt_pk_f32_fp8((int)b, false);
    v2f b1 = __builtin_amdgcn_cvt_pk_f32_fp8((int)b, true);
    float d0 = a0.x - b0.x;
    float d1 = a0.y - b0.y;
    float d2 = a1.x - b1.x;
    float d3 = a1.y - b1.y;
    return d0 * d0 + d1 * d1 + d2 * d2 + d3 * d3;
}
#else
__device__ __forceinline__ float ssd4(unsigned a, unsigned b) {
    float s = 0.0f;
#pragma unroll
    for (int i = 0; i < 4; ++i) {
        float va = fp82f((a >> (8 * i)) & 0xFFu);
        float vb = fp82f((b >> (8 * i)) & 0xFFu);
        float d = va - vb;
        s += d * d;
    }
    return s;
}
#endif

// ===================== degree: R=2, fp16-packed LDS hist =====================
// ds_pk_add_f16: packed-fp16 atomic add into LDS (dword-granular, CDNA3+).
// Element t (half) lives at byte (t>>1)*4; lane deposits its weight into the
// low or high half via the packed operand. Per-slice cells get ~0.25 hits on
// average, so fp16 accumulation noise (~5e-4) << fp8 quantization (~6%).
// Geometry: grid 256 = 1 block/CU exactly; s = b&127, r = b>>7 puts the two
// readers of a slice on the SAME XCD (b ≡ b+128 mod 8) -> 2nd read is L2-hit.

__device__ __forceinline__ void pk_hist_add(unsigned lds_base, int t, float wv) {
    const unsigned hb   = (unsigned)__half_as_ushort(__float2half(wv));
    const unsigned data = (t & 1) ? (hb << 16) : hb;
    const unsigned addr = lds_base + (unsigned)(t >> 1) * 4u;
    asm volatile("ds_pk_add_f16 %0, %1" :: "v"(addr), "v"(data) : "memory");
}

__global__ __launch_bounds__(B_DEG) void lap_degree_r2(
        const int* __restrict__ rows, const float* __restrict__ w,
        __half* __restrict__ shadows, float* __restrict__ out) {
    extern __shared__ __align__(16) unsigned char histb[];
    const int b  = blockIdx.x;
    const int s  = b & (S2 - 1);
    const int r  = b >> 7;
    const int lo = r * NPR2;
    const unsigned lds_base = (unsigned)(size_t)histb;

    if (b == 0 && threadIdx.x == 0) out[0] = 0.0f;

    uint4* h4 = (uint4*)histb;                       // 100000 B = 6250 uint4
    for (int i = threadIdx.x; i < DYN2 / 16; i += B_DEG)
        h4[i] = make_uint4(0u, 0u, 0u, 0u);
    __syncthreads();

    const int base = s * EPS2;
    for (int g = threadIdx.x; g < EPS2 / 4; g += B_DEG) {
        const int e = base + g * 4;                  // exact coverage, no tail
        int4   r4 = *(const int4*)(rows + e);
        float4 w4 = *(const float4*)(w + e);
        int t;
        t = r4.x - lo; if ((unsigned)t < (unsigned)NPR2) pk_hist_add(lds_base, t, w4.x);
        t = r4.y - lo; if ((unsigned)t < (unsigned)NPR2) pk_hist_add(lds_base, t, w4.y);
        t = r4.z - lo; if ((unsigned)t < (unsigned)NPR2) pk_hist_add(lds_base, t, w4.z);
        t = r4.w - lo; if ((unsigned)t < (unsigned)NPR2) pk_hist_add(lds_base, t, w4.w);
    }
    __syncthreads();

    // shadows are fp16 already: raw 16B copy, no conversion
    uint4* dst = (uint4*)(shadows + (size_t)s * N_NODES + lo);   // 16B-aligned
    for (int i = threadIdx.x; i < DYN2 / 16; i += B_DEG) dst[i] = h4[i];
}

// ===================== degree fallback: static 50 KB fp32, R=8 =====================

__global__ __launch_bounds__(B_DEG) void lap_degree_static(
        const int* __restrict__ rows, const float* __restrict__ w,
        __half* __restrict__ shadows, float* __restrict__ out) {
    __shared__ float hist[NPR_ST];
    const int r  = blockIdx.x & (R_ST - 1);
    const int s  = blockIdx.x >> 3;
    const int lo = r * NPR_ST;

    if (blockIdx.x == 0 && threadIdx.x == 0) out[0] = 0.0f;

    for (int i = threadIdx.x; i < NPR_ST; i += B_DEG) hist[i] = 0.0f;
    __syncthreads();

    const int base = s * EPS_ST;
    for (int g = threadIdx.x; g < EPS_ST / 4; g += B_DEG) {
        const int e = base + g * 4;
        int4   r4 = *(const int4*)(rows + e);
        float4 w4 = *(const float4*)(w + e);
        int t;
        t = r4.x - lo; if ((unsigned)t < (unsigned)NPR_ST) atomicAdd(&hist[t], w4.x);
        t = r4.y - lo; if ((unsigned)t < (unsigned)NPR_ST) atomicAdd(&hist[t], w4.y);
        t = r4.z - lo; if ((unsigned)t < (unsigned)NPR_ST) atomicAdd(&hist[t], w4.z);
        t = r4.w - lo; if ((unsigned)t < (unsigned)NPR_ST) atomicAdd(&hist[t], w4.w);
    }
    __syncthreads();

    __half* dst = shadows + (size_t)s * N_NODES + lo;
    for (int i = threadIdx.x; i < NPR_ST; i += B_DEG) dst[i] = __float2half(hist[i]);
}

// ===================== parallel shadow reduce -> rsqrt -> fp8 yhat =====================
// 64 nodes/block, wave wv sums slices {wv, wv+4, ...} via 4 independent load
// streams, LDS combine, wave 0 encodes fp8.  (unchanged — A/B control)

__global__ __launch_bounds__(256) void lap_yhat_par(
        const __half* __restrict__ shadows,
        const float* __restrict__ y,
        unsigned char* __restrict__ yhat, int S) {
    const int lane = threadIdx.x & 63;
    const int wv   = threadIdx.x >> 6;
    const int n    = blockIdx.x * 64 + lane;

    float a0 = 0.0f, a1 = 0.0f, a2 = 0.0f, a3 = 0.0f;
    if (n < N_NODES) {
        const __half* p = shadows + n;
        int s = wv;
        for (; s + 12 < S; s += 16) {            // 4 independent load streams
            a0 += __half2float(p[(size_t)(s)      * N_NODES]);
            a1 += __half2float(p[(size_t)(s + 4)  * N_NODES]);
            a2 += __half2float(p[(size_t)(s + 8)  * N_NODES]);
            a3 += __half2float(p[(size_t)(s + 12) * N_NODES]);
        }
        for (; s < S; s += 4)
            a0 += __half2float(p[(size_t)s * N_NODES]);
    }

    __shared__ float sm[4][64];
    sm[wv][lane] = (a0 + a1) + (a2 + a3);
    __syncthreads();

    if (wv == 0 && n < N_NODES) {
        const float deg = (sm[0][lane] + sm[1][lane]) + (sm[2][lane] + sm[3][lane]);
        const float inv = rsqrtf(deg);
        const float4* yr = (const float4*)(y + (size_t)n * N_CLASSES);
        uint4 o;
        unsigned* op = (unsigned*)&o;
#pragma unroll
        for (int j = 0; j < 4; ++j) {
            float4 v = yr[j];
            op[j] =  f2fp8(v.x * inv)
                  | (f2fp8(v.y * inv) << 8)
                  | (f2fp8(v.z * inv) << 16)
                  | (f2fp8(v.w * inv) << 24);
        }
        *(uint4*)(yhat + (size_t)n * N_CLASSES) = o;
    }
}

// ===================== edge pass: fp8 HW decode, fused mean =====================
// (byte-identical — A/B control)

__global__ void lap_edge_fp8(const int* __restrict__ rows,
                             const int* __restrict__ cols,
                             const float* __restrict__ w,
                             const unsigned char* __restrict__ yhat,
                             float* __restrict__ out) {
    const int tid = blockIdx.x * blockDim.x + threadIdx.x;
    const long e0 = (long)tid * KE;
    float local = 0.0f;
    if (e0 < N_EDGES) {
        int4   ra = *(const int4*)(rows + e0);
        int4   rb = *(const int4*)(rows + e0 + 4);
        int4   ca = *(const int4*)(cols + e0);
        int4   cb = *(const int4*)(cols + e0 + 4);
        float4 wa = *(const float4*)(w + e0);
        float4 wb = *(const float4*)(w + e0 + 4);

        const int ri[KE] = {ra.x, ra.y, ra.z, ra.w, rb.x, rb.y, rb.z, rb.w};
        const int ci[KE] = {ca.x, ca.y, ca.z, ca.w, cb.x, cb.y, cb.z, cb.w};
        const float wv[KE] = {wa.x, wa.y, wa.z, wa.w, wb.x, wb.y, wb.z, wb.w};

        uint4 A[KE], B[KE];
#pragma unroll
        for (int k = 0; k < KE; ++k) {
            A[k] = *(const uint4*)(yhat + (size_t)ri[k] * N_CLASSES);
            B[k] = *(const uint4*)(yhat + (size_t)ci[k] * N_CLASSES);
        }
#pragma unroll
        for (int k = 0; k < KE; ++k) {
            float s = ssd4(A[k].x, B[k].x) + ssd4(A[k].y, B[k].y)
                    + ssd4(A[k].z, B[k].z) + ssd4(A[k].w, B[k].w);
            local += wv[k] * sqrtf(s);
        }
    }
#pragma unroll
    for (int off = 32; off > 0; off >>= 1) local += __shfl_down(local, off, 64);
    __shared__ float sm[4];
    const int lane = threadIdx.x & 63;
    const int wid  = threadIdx.x >> 6;
    if (lane == 0) sm[wid] = local;
    __syncthreads();
    if (threadIdx.x == 0)
        atomicAdd(out, (sm[0] + sm[1] + sm[2] + sm[3]) * (1.0f / (float)N_EDGES));
}

// ===================== low fallback (tiny ws) =====================

__global__ void lap_degree_kernel(const int* __restrict__ rows,
                                  const float* __restrict__ w,
                                  float* __restrict__ degree) {
    int i = blockIdx.x * blockDim.x + threadIdx.x;
    if (i < N_EDGES) atomicAdd(&degree[rows[i]], w[i]);
}

__global__ void lap_invd_kernel(const float* __restrict__ degree,
                                float* __restrict__ invd) {
    int i = blockIdx.x * blockDim.x + threadIdx.x;
    if (i < N_NODES) invd[i] = rsqrtf(degree[i]);
}

__global__ void lap_edge_kernel(const int* __restrict__ rows,
                                const int* __restrict__ cols,
                                const float* __restrict__ w,
                                const float* __restrict__ y,
                                const float* __restrict__ invd,
                                float* __restrict__ out) {
    int i = blockIdx.x * blockDim.x + threadIdx.x;
    float local = 0.0f;
    if (i < N_EDGES) {
        int r = rows[i], c = cols[i];
        float dr = invd[r], dc = invd[c];
        const float4* yr = (const float4*)(y + (size_t)r * N_CLASSES);
        const float4* yc = (const float4*)(y + (size_t)c * N_CLASSES);
        float s = 0.0f;
#pragma unroll
        for (int j = 0; j < N_CLASSES / 4; ++j) {
            float4 a = yr[j], b = yc[j];
            float d0 = a.x * dr - b.x * dc;
            float d1 = a.y * dr - b.y * dc;
            float d2 = a.z * dr - b.z * dc;
            float d3 = a.w * dr - b.w * dc;
            s += d0 * d0 + d1 * d1 + d2 * d2 + d3 * d3;
        }
        local = w[i] * sqrtf(s);
    }
#pragma unroll
    for (int off = 32; off > 0; off >>= 1) local += __shfl_down(local, off, 64);
    __shared__ float sm[4];
    int lane = threadIdx.x & 63, wid = threadIdx.x >> 6;
    if (lane == 0) sm[wid] = local;
    __syncthreads();
    if (threadIdx.x == 0)
        atomicAdd(out, (sm[0] + sm[1] + sm[2] + sm[3]) * (1.0f / (float)N_EDGES));
}

// ===================== launch =====================

extern "C" void kernel_launch(void* const* d_in, const int* in_sizes, int n_in,
                              void* d_out, int out_size, void* d_ws, size_t ws_size,
                              hipStream_t stream) {
    const int*   edge_index = (const int*)d_in[0];   // [rows | cols]
    const float* w          = (const float*)d_in[1];
    const float* y          = (const float*)d_in[2];
    float*       out        = (float*)d_out;

    const int* rows = edge_index;
    const int* cols = edge_index + N_EDGES;
    const int  B = 256;

    // layout: [shadows: S2*N halves (25.6 MB)][yhat: N*16 fp8 bytes]
    const size_t sh_bytes   = (size_t)S2 * N_NODES * sizeof(__half);
    const size_t need_super = sh_bytes + (size_t)N_NODES * N_CLASSES;

    const int edge_blocks = (N_EDGES / KE + B - 1) / B;   // 1563
    const int yhat_blocks = (N_NODES + 63) / 64;          // 1563

    if (ws_size >= need_super) {
        __half*        shadows = (__half*)d_ws;
        unsigned char* yhat    = (unsigned char*)d_ws + sh_bytes;

        hipError_t ok = hipFuncSetAttribute(
            reinterpret_cast<const void*>(lap_degree_r2),
            hipFuncAttributeMaxDynamicSharedMemorySize, DYN2);

        if (ok == hipSuccess) {
            lap_degree_r2<<<R2 * S2, B_DEG, DYN2, stream>>>(rows, w, shadows, out);
            lap_yhat_par<<<yhat_blocks, B, 0, stream>>>(shadows, y, yhat, S2);
        } else {
            lap_degree_static<<<R_ST * S_ST, B_DEG, 0, stream>>>(rows, w, shadows, out);
            lap_yhat_par<<<yhat_blocks, B, 0, stream>>>(shadows, y, yhat, S_ST);
        }
        lap_edge_fp8<<<edge_blocks, B, 0, stream>>>(rows, cols, w, yhat, out);
    } else {
        float* degree = (float*)d_ws;
        float* invd   = degree + N_NODES;
        hipMemsetAsync(d_out, 0, sizeof(float), stream);
        hipMemsetAsync(d_ws, 0, (size_t)N_NODES * sizeof(float), stream);
        lap_degree_kernel<<<(N_EDGES + B - 1) / B, B, 0, stream>>>(rows, w, degree);
        lap_invd_kernel<<<(N_NODES + B - 1) / B, B, 0, stream>>>(degree, invd);
        lap_edge_kernel<<<(N_EDGES + B - 1) / B, B, 0, stream>>>(rows, cols, w, y, invd, out);
    }
}

// Round 4
// 139.538 us; speedup vs baseline: 1.9995x; 1.0005x over previous
//
#include <hip/hip_runtime.h>
#include <hip/hip_fp16.h>

#define N_NODES   100000
#define N_CLASSES 16
#define N_EDGES   3200000

// ---- degree: R=2 ranges, fp16-packed hist, 100 KB dynamic LDS, 1 block/CU ----
#define R2        2
#define NPR2      50000                 // nodes per range (fp16 -> 100000 B LDS)
#define DYN2      (NPR2 * 2)            // 100000 B dynamic LDS
#define S2        128                   // slices -> grid 256 (1 block/CU, exact)
#define EPS2      25000                 // 128*25000 == N_EDGES exactly, no tail

// ---- degree fallback: static 50 KB fp32, R=8 ----
#define R_ST      8
#define NPR_ST    12500
#define S_ST      64
#define EPS_ST    50000

#define B_DEG     1024
#define KE        8                     // edges per thread, edge pass
#define EDGE_BLOCKS ((N_EDGES / KE + 255) / 256)   // 1563

// ===================== fp8 e4m3 helpers =====================
// Manual encode produces OCP e4m3fn bit patterns (bias 7, max 448),
// so the HW decoder v_cvt_pk_f32_fp8 reads them exactly. (verified pass)

__device__ __forceinline__ unsigned f2fp8(float f) {
    unsigned u = __float_as_uint(f);
    unsigned s = (u >> 24) & 0x80u;
    float g = fabsf(f) * 0x1p-120f;
    unsigned gu = __float_as_uint(g);
    gu += 0x7FFFFu + ((gu >> 20) & 1u);       // RNE at bit 20
    unsigned mag = gu >> 20;
    if (mag > 0x7Eu) mag = 0x7Eu;             // clamp to 448
    return s | mag;
}

__device__ __forceinline__ float fp82f(unsigned b) {
    unsigned u = ((b & 0x80u) << 24) | ((b & 0x7Fu) << 20);
    return __uint_as_float(u) * 0x1p120f;
}

#if defined(__has_builtin)
#if __has_builtin(__builtin_amdgcn_cvt_pk_f32_fp8)
#define HAVE_HW_FP8 1
#endif
#endif

#ifdef HAVE_HW_FP8
typedef float v2f __attribute__((ext_vector_type(2)));
__device__ __forceinline__ float ssd4(unsigned a, unsigned b) {
    v2f a0 = __builtin_amdgcn_cvt_pk_f32_fp8((int)a, false);
    v2f a1 = __builtin_amdgcn_cvt_pk_f32_fp8((int)a, true);
    v2f b0 = __builtin_amdgcn_cvt_pk_f32_fp8((int)b, false);
    v2f b1 = __builtin_amdgcn_cvt_pk_f32_fp8((int)b, true);
    float d0 = a0.x - b0.x;
    float d1 = a0.y - b0.y;
    float d2 = a1.x - b1.x;
    float d3 = a1.y - b1.y;
    return d0 * d0 + d1 * d1 + d2 * d2 + d3 * d3;
}
#else
__device__ __forceinline__ float ssd4(unsigned a, unsigned b) {
    float s = 0.0f;
#pragma unroll
    for (int i = 0; i < 4; ++i) {
        float va = fp82f((a >> (8 * i)) & 0xFFu);
        float vb = fp82f((b >> (8 * i)) & 0xFFu);
        float d = va - vb;
        s += d * d;
    }
    return s;
}
#endif

// ===================== degree: R=2, fp16-packed LDS hist =====================
// (byte-identical to round-3 — A/B control)

__device__ __forceinline__ void pk_hist_add(unsigned lds_base, int t, float wv) {
    const unsigned hb   = (unsigned)__half_as_ushort(__float2half(wv));
    const unsigned data = (t & 1) ? (hb << 16) : hb;
    const unsigned addr = lds_base + (unsigned)(t >> 1) * 4u;
    asm volatile("ds_pk_add_f16 %0, %1" :: "v"(addr), "v"(data) : "memory");
}

__global__ __launch_bounds__(B_DEG) void lap_degree_r2(
        const int* __restrict__ rows, const float* __restrict__ w,
        __half* __restrict__ shadows) {
    extern __shared__ __align__(16) unsigned char histb[];
    const int b  = blockIdx.x;
    const int s  = b & (S2 - 1);
    const int r  = b >> 7;
    const int lo = r * NPR2;
    const unsigned lds_base = (unsigned)(size_t)histb;

    uint4* h4 = (uint4*)histb;                       // 100000 B = 6250 uint4
    for (int i = threadIdx.x; i < DYN2 / 16; i += B_DEG)
        h4[i] = make_uint4(0u, 0u, 0u, 0u);
    __syncthreads();

    const int base = s * EPS2;
    for (int g = threadIdx.x; g < EPS2 / 4; g += B_DEG) {
        const int e = base + g * 4;                  // exact coverage, no tail
        int4   r4 = *(const int4*)(rows + e);
        float4 w4 = *(const float4*)(w + e);
        int t;
        t = r4.x - lo; if ((unsigned)t < (unsigned)NPR2) pk_hist_add(lds_base, t, w4.x);
        t = r4.y - lo; if ((unsigned)t < (unsigned)NPR2) pk_hist_add(lds_base, t, w4.y);
        t = r4.z - lo; if ((unsigned)t < (unsigned)NPR2) pk_hist_add(lds_base, t, w4.z);
        t = r4.w - lo; if ((unsigned)t < (unsigned)NPR2) pk_hist_add(lds_base, t, w4.w);
    }
    __syncthreads();

    // shadows are fp16 already: raw 16B copy, no conversion
    uint4* dst = (uint4*)(shadows + (size_t)s * N_NODES + lo);   // 16B-aligned
    for (int i = threadIdx.x; i < DYN2 / 16; i += B_DEG) dst[i] = h4[i];
}

// ===================== degree fallback: static 50 KB fp32, R=8 =====================

__global__ __launch_bounds__(B_DEG) void lap_degree_static(
        const int* __restrict__ rows, const float* __restrict__ w,
        __half* __restrict__ shadows) {
    __shared__ float hist[NPR_ST];
    const int r  = blockIdx.x & (R_ST - 1);
    const int s  = blockIdx.x >> 3;
    const int lo = r * NPR_ST;

    for (int i = threadIdx.x; i < NPR_ST; i += B_DEG) hist[i] = 0.0f;
    __syncthreads();

    const int base = s * EPS_ST;
    for (int g = threadIdx.x; g < EPS_ST / 4; g += B_DEG) {
        const int e = base + g * 4;
        int4   r4 = *(const int4*)(rows + e);
        float4 w4 = *(const float4*)(w + e);
        int t;
        t = r4.x - lo; if ((unsigned)t < (unsigned)NPR_ST) atomicAdd(&hist[t], w4.x);
        t = r4.y - lo; if ((unsigned)t < (unsigned)NPR_ST) atomicAdd(&hist[t], w4.y);
        t = r4.z - lo; if ((unsigned)t < (unsigned)NPR_ST) atomicAdd(&hist[t], w4.z);
        t = r4.w - lo; if ((unsigned)t < (unsigned)NPR_ST) atomicAdd(&hist[t], w4.w);
    }
    __syncthreads();

    __half* dst = shadows + (size_t)s * N_NODES + lo;
    for (int i = threadIdx.x; i < NPR_ST; i += B_DEG) dst[i] = __float2half(hist[i]);
}

// ===================== parallel shadow reduce -> rsqrt -> fp8 yhat =====================
// (byte-identical — A/B control)

__global__ __launch_bounds__(256) void lap_yhat_par(
        const __half* __restrict__ shadows,
        const float* __restrict__ y,
        unsigned char* __restrict__ yhat, int S) {
    const int lane = threadIdx.x & 63;
    const int wv   = threadIdx.x >> 6;
    const int n    = blockIdx.x * 64 + lane;

    float a0 = 0.0f, a1 = 0.0f, a2 = 0.0f, a3 = 0.0f;
    if (n < N_NODES) {
        const __half* p = shadows + n;
        int s = wv;
        for (; s + 12 < S; s += 16) {            // 4 independent load streams
            a0 += __half2float(p[(size_t)(s)      * N_NODES]);
            a1 += __half2float(p[(size_t)(s + 4)  * N_NODES]);
            a2 += __half2float(p[(size_t)(s + 8)  * N_NODES]);
            a3 += __half2float(p[(size_t)(s + 12) * N_NODES]);
        }
        for (; s < S; s += 4)
            a0 += __half2float(p[(size_t)s * N_NODES]);
    }

    __shared__ float sm[4][64];
    sm[wv][lane] = (a0 + a1) + (a2 + a3);
    __syncthreads();

    if (wv == 0 && n < N_NODES) {
        const float deg = (sm[0][lane] + sm[1][lane]) + (sm[2][lane] + sm[3][lane]);
        const float inv = rsqrtf(deg);
        const float4* yr = (const float4*)(y + (size_t)n * N_CLASSES);
        uint4 o;
        unsigned* op = (unsigned*)&o;
#pragma unroll
        for (int j = 0; j < 4; ++j) {
            float4 v = yr[j];
            op[j] =  f2fp8(v.x * inv)
                  | (f2fp8(v.y * inv) << 8)
                  | (f2fp8(v.z * inv) << 16)
                  | (f2fp8(v.w * inv) << 24);
        }
        *(uint4*)(yhat + (size_t)n * N_CLASSES) = o;
    }
}

// ===================== edge pass: fp8 HW decode, PARTIAL SUMS =====================
// Change this round: the per-block single-address atomicAdd(out) is replaced
// by a plain store of the block partial sum. 1563 same-address device-scope
// atomics serialize at the coherence point (~35 ns each ≈ 55 us tail — the
// dominant cost inferred from the R0-R3 budget). Compute body is unchanged.

__global__ void lap_edge_fp8(const int* __restrict__ rows,
                             const int* __restrict__ cols,
                             const float* __restrict__ w,
                             const unsigned char* __restrict__ yhat,
                             float* __restrict__ partial) {
    const int tid = blockIdx.x * blockDim.x + threadIdx.x;
    const long e0 = (long)tid * KE;
    float local = 0.0f;
    if (e0 < N_EDGES) {
        int4   ra = *(const int4*)(rows + e0);
        int4   rb = *(const int4*)(rows + e0 + 4);
        int4   ca = *(const int4*)(cols + e0);
        int4   cb = *(const int4*)(cols + e0 + 4);
        float4 wa = *(const float4*)(w + e0);
        float4 wb = *(const float4*)(w + e0 + 4);

        const int ri[KE] = {ra.x, ra.y, ra.z, ra.w, rb.x, rb.y, rb.z, rb.w};
        const int ci[KE] = {ca.x, ca.y, ca.z, ca.w, cb.x, cb.y, cb.z, cb.w};
        const float wv[KE] = {wa.x, wa.y, wa.z, wa.w, wb.x, wb.y, wb.z, wb.w};

        uint4 A[KE], B[KE];
#pragma unroll
        for (int k = 0; k < KE; ++k) {
            A[k] = *(const uint4*)(yhat + (size_t)ri[k] * N_CLASSES);
            B[k] = *(const uint4*)(yhat + (size_t)ci[k] * N_CLASSES);
        }
#pragma unroll
        for (int k = 0; k < KE; ++k) {
            float s = ssd4(A[k].x, B[k].x) + ssd4(A[k].y, B[k].y)
                    + ssd4(A[k].z, B[k].z) + ssd4(A[k].w, B[k].w);
            local += wv[k] * sqrtf(s);
        }
    }
#pragma unroll
    for (int off = 32; off > 0; off >>= 1) local += __shfl_down(local, off, 64);
    __shared__ float sm[4];
    const int lane = threadIdx.x & 63;
    const int wid  = threadIdx.x >> 6;
    if (lane == 0) sm[wid] = local;
    __syncthreads();
    if (threadIdx.x == 0)
        partial[blockIdx.x] = sm[0] + sm[1] + sm[2] + sm[3];   // plain store
}

// ===================== final reduce: 1563 partials -> mean =====================

__global__ __launch_bounds__(1024) void lap_reduce(
        const float* __restrict__ partial, float* __restrict__ out) {
    float local = 0.0f;
    for (int i = threadIdx.x; i < EDGE_BLOCKS; i += 1024) local += partial[i];
#pragma unroll
    for (int off = 32; off > 0; off >>= 1) local += __shfl_down(local, off, 64);
    __shared__ float sm[16];
    const int lane = threadIdx.x & 63;
    const int wid  = threadIdx.x >> 6;
    if (lane == 0) sm[wid] = local;
    __syncthreads();
    if (threadIdx.x == 0) {
        float t = 0.0f;
#pragma unroll
        for (int i = 0; i < 16; ++i) t += sm[i];
        out[0] = t * (1.0f / (float)N_EDGES);
    }
}

// ===================== low fallback (tiny ws) =====================

__global__ void lap_degree_kernel(const int* __restrict__ rows,
                                  const float* __restrict__ w,
                                  float* __restrict__ degree) {
    int i = blockIdx.x * blockDim.x + threadIdx.x;
    if (i < N_EDGES) atomicAdd(&degree[rows[i]], w[i]);
}

__global__ void lap_invd_kernel(const float* __restrict__ degree,
                                float* __restrict__ invd) {
    int i = blockIdx.x * blockDim.x + threadIdx.x;
    if (i < N_NODES) invd[i] = rsqrtf(degree[i]);
}

__global__ void lap_edge_kernel(const int* __restrict__ rows,
                                const int* __restrict__ cols,
                                const float* __restrict__ w,
                                const float* __restrict__ y,
                                const float* __restrict__ invd,
                                float* __restrict__ out) {
    int i = blockIdx.x * blockDim.x + threadIdx.x;
    float local = 0.0f;
    if (i < N_EDGES) {
        int r = rows[i], c = cols[i];
        float dr = invd[r], dc = invd[c];
        const float4* yr = (const float4*)(y + (size_t)r * N_CLASSES);
        const float4* yc = (const float4*)(y + (size_t)c * N_CLASSES);
        float s = 0.0f;
#pragma unroll
        for (int j = 0; j < N_CLASSES / 4; ++j) {
            float4 a = yr[j], b = yc[j];
            float d0 = a.x * dr - b.x * dc;
            float d1 = a.y * dr - b.y * dc;
            float d2 = a.z * dr - b.z * dc;
            float d3 = a.w * dr - b.w * dc;
            s += d0 * d0 + d1 * d1 + d2 * d2 + d3 * d3;
        }
        local = w[i] * sqrtf(s);
    }
#pragma unroll
    for (int off = 32; off > 0; off >>= 1) local += __shfl_down(local, off, 64);
    __shared__ float sm[4];
    int lane = threadIdx.x & 63, wid = threadIdx.x >> 6;
    if (lane == 0) sm[wid] = local;
    __syncthreads();
    if (threadIdx.x == 0)
        atomicAdd(out, (sm[0] + sm[1] + sm[2] + sm[3]) * (1.0f / (float)N_EDGES));
}

// ===================== launch =====================

extern "C" void kernel_launch(void* const* d_in, const int* in_sizes, int n_in,
                              void* d_out, int out_size, void* d_ws, size_t ws_size,
                              hipStream_t stream) {
    const int*   edge_index = (const int*)d_in[0];   // [rows | cols]
    const float* w          = (const float*)d_in[1];
    const float* y          = (const float*)d_in[2];
    float*       out        = (float*)d_out;

    const int* rows = edge_index;
    const int* cols = edge_index + N_EDGES;
    const int  B = 256;

    // layout: [shadows: S2*N halves (25.6 MB)][yhat: N*16 fp8][partial: 1563 f32]
    const size_t sh_bytes   = (size_t)S2 * N_NODES * sizeof(__half);
    const size_t yh_bytes   = (size_t)N_NODES * N_CLASSES;
    const size_t need_super = sh_bytes + yh_bytes + (size_t)EDGE_BLOCKS * sizeof(float);

    const int yhat_blocks = (N_NODES + 63) / 64;          // 1563

    if (ws_size >= need_super) {
        __half*        shadows = (__half*)d_ws;
        unsigned char* yhat    = (unsigned char*)d_ws + sh_bytes;
        float*         partial = (float*)((unsigned char*)d_ws + sh_bytes + yh_bytes);

        hipError_t ok = hipFuncSetAttribute(
            reinterpret_cast<const void*>(lap_degree_r2),
            hipFuncAttributeMaxDynamicSharedMemorySize, DYN2);

        if (ok == hipSuccess) {
            lap_degree_r2<<<R2 * S2, B_DEG, DYN2, stream>>>(rows, w, shadows);
            lap_yhat_par<<<yhat_blocks, B, 0, stream>>>(shadows, y, yhat, S2);
        } else {
            lap_degree_static<<<R_ST * S_ST, B_DEG, 0, stream>>>(rows, w, shadows);
            lap_yhat_par<<<yhat_blocks, B, 0, stream>>>(shadows, y, yhat, S_ST);
        }
        lap_edge_fp8<<<EDGE_BLOCKS, B, 0, stream>>>(rows, cols, w, yhat, partial);
        lap_reduce<<<1, 1024, 0, stream>>>(partial, out);
    } else {
        float* degree = (float*)d_ws;
        float* invd   = degree + N_NODES;
        hipMemsetAsync(d_out, 0, sizeof(float), stream);
        hipMemsetAsync(d_ws, 0, (size_t)N_NODES * sizeof(float), stream);
        lap_degree_kernel<<<(N_EDGES + B - 1) / B, B, 0, stream>>>(rows, w, degree);
        lap_invd_kernel<<<(N_NODES + B - 1) / B, B, 0, stream>>>(degree, invd);
        lap_edge_kernel<<<(N_EDGES + B - 1) / B, B, 0, stream>>>(rows, cols, w, y, invd, out);
    }
}